// Round 3
// baseline (1160.228 us; speedup 1.0000x reference)
//
#include <hip/hip_runtime.h>
#include <math.h>

#define F_DIM 512
#define H_DIM 256

using v8bf  = __attribute__((ext_vector_type(8))) __bf16;
using f32x4 = __attribute__((ext_vector_type(4))) float;

// ---------- scalar format helpers (no half/fp8 API dependencies) ----------
__device__ __forceinline__ float bf2f(unsigned short u) {
    return __uint_as_float(((unsigned int)u) << 16);
}
__device__ __forceinline__ unsigned short f2bf(float f) {
    unsigned int x = __float_as_uint(f);
    unsigned int r = x + 0x7FFFu + ((x >> 16) & 1u);  // RNE
    return (unsigned short)(r >> 16);
}
// OCP e4m3: decode byte -> float (exact, incl. subnormals; no NaN in data)
__device__ __forceinline__ float fp8_dec(unsigned b) {
    unsigned em = b & 0x7Fu;
    float v = (em >= 8u) ? __uint_as_float((em + 960u) << 20)   // 2^(e-7)*(1+m/8)
                         : (float)em * 0.001953125f;            // m * 2^-9
    return (b & 0x80u) ? -v : v;
}
// float -> e4m3 with RNE (|f| << 448 so no saturation path needed)
__device__ __forceinline__ unsigned fp8_enc(float f) {
    unsigned bits = __float_as_uint(f);
    unsigned s = (bits >> 31) << 7;
    unsigned r = bits + 0x7FFFFu + ((bits >> 20) & 1u);   // round mantissa 23->3
    int e = (int)((r >> 23) & 0xFF);
    unsigned em;
    if (e >= 121) em = (unsigned)(((e - 120) << 3) | ((r >> 20) & 7u));
    else          em = (unsigned)__float2int_rn(fabsf(f) * 512.0f);  // subnormal
    return s | em;
}

// ---------- degree histogram ----------
__global__ void hist_kernel(const int* __restrict__ src, const int* __restrict__ dst,
                            int E, int* degO, int* degI) {
    int stride = gridDim.x * blockDim.x;
    for (int e = blockIdx.x * blockDim.x + threadIdx.x; e < E; e += stride) {
        atomicAdd(&degO[src[e]], 1);
        atomicAdd(&degI[dst[e]], 1);
    }
}

// ---------- norms ----------
__global__ void norm_kernel(const int* __restrict__ degO, const int* __restrict__ degI,
                            int n, float* nsrc, float* ndst) {
    int i = blockIdx.x * blockDim.x + threadIdx.x;
    if (i < n) {
        nsrc[i] = rsqrtf(fmaxf((float)degO[i], 1.0f));
        ndst[i] = rsqrtf(fmaxf((float)degI[i], 1.0f));
    }
}

// ---------- exclusive scan of in-degree (3-kernel) ----------
__global__ void scan1_kernel(const int* __restrict__ deg, int n, int* blocksums) {
    __shared__ int sm[256];
    int b = blockIdx.x, t = threadIdx.x;
    int base = b * 1024 + t * 4;
    int s = 0;
#pragma unroll
    for (int i = 0; i < 4; i++) { int idx = base + i; if (idx < n) s += deg[idx]; }
    sm[t] = s; __syncthreads();
    for (int off = 128; off > 0; off >>= 1) {
        if (t < off) sm[t] += sm[t + off];
        __syncthreads();
    }
    if (t == 0) blocksums[b] = sm[0];
}

__global__ void scan2_kernel(const int* __restrict__ blocksums, int nb, int* blockoffs) {
    if (threadIdx.x == 0 && blockIdx.x == 0) {
        int run = 0;
        for (int i = 0; i < nb; i++) { blockoffs[i] = run; run += blocksums[i]; }
    }
}

__global__ void scan3_kernel(const int* __restrict__ deg, int n,
                             const int* __restrict__ blockoffs, int* row_start) {
    __shared__ int sm[256];
    int b = blockIdx.x, t = threadIdx.x;
    int base = b * 1024 + t * 4;
    int v[4]; int s = 0;
#pragma unroll
    for (int i = 0; i < 4; i++) {
        int idx = base + i;
        v[i] = (idx < n) ? deg[idx] : 0;
        s += v[i];
    }
    sm[t] = s; __syncthreads();
    for (int off = 1; off < 256; off <<= 1) {
        int x = sm[t];
        int y = (t >= off) ? sm[t - off] : 0;
        __syncthreads();
        sm[t] = x + y;
        __syncthreads();
    }
    int run = blockoffs[b] + sm[t] - s;
#pragma unroll
    for (int i = 0; i < 4; i++) {
        int idx = base + i;
        if (idx < n) row_start[idx] = run;
        run += v[i];
    }
}

// ---------- CSR fill ----------
__global__ void csr_fill_kernel(const int* __restrict__ src, const int* __restrict__ dst,
                                int E, const int* __restrict__ row_start,
                                int* cursor, int* esrc) {
    int stride = gridDim.x * blockDim.x;
    for (int e = blockIdx.x * blockDim.x + threadIdx.x; e < E; e += stride) {
        int d = dst[e];
        int pos = atomicAdd(&cursor[d], 1);
        esrc[row_start[d] + pos] = src[e];
    }
}

// ---------- weight transpose+cast: Wt[n][k] = bf16(W[k][n]) ----------
__global__ void wt_kernel(const float* __restrict__ W, unsigned short* __restrict__ Wt, int K) {
    int idx = blockIdx.x * 256 + threadIdx.x;  // over 256*K
    if (idx < 256 * K) {
        int n = idx / K, k = idx - n * K;
        Wt[idx] = f2bf(W[(size_t)k * 256 + n]);
    }
}

// ---------- MFMA GEMM: Xout(fp8) = (A [*scale]) @ Wt^T ; Wt is [256][K] bf16 ----------
// block = 256 threads (4 waves), BM=64, BN=256, BK=32. Wave wv owns cols wv*64..+63.
// Swapped-operand MFMA: acc = mfma(b_frag, a_frag) -> lane holds 4 consecutive cols.
template<int KDIM, bool A_FP32>
__global__ __launch_bounds__(256) void gemm_mfma_kernel(
    const void* __restrict__ Aptr, const float* __restrict__ scale,
    const unsigned short* __restrict__ Wt, unsigned char* __restrict__ Xout, int M) {
    __shared__ unsigned short As[64 * 40];    // [m][k] pad 8 -> 80B row stride
    __shared__ unsigned short Bs[256 * 40];   // [n][k] pad 8

    const int tid = threadIdx.x;
    const int wv = tid >> 6, ln = tid & 63;
    const int m0 = blockIdx.x * 64;
    const int sr = tid >> 2;        // staging row 0..63
    const int sc = tid & 3;         // staging k-chunk 0..3 (8 elems)

    f32x4 acc[4][4];
#pragma unroll
    for (int i = 0; i < 4; i++)
#pragma unroll
        for (int j = 0; j < 4; j++) acc[i][j] = (f32x4){0.f, 0.f, 0.f, 0.f};

    const int gr = m0 + sr;
    const bool rok = (gr < M);
    float ns = 0.0f;
    if (A_FP32 && rok) ns = scale[gr];

    for (int k0 = 0; k0 < KDIM; k0 += 32) {
        // ---- stage A (64x32 bf16) ----
        if (A_FP32) {
            const float* A = (const float*)Aptr;
            float4 va = make_float4(0, 0, 0, 0), vb = make_float4(0, 0, 0, 0);
            if (rok) {
                const float* p = A + (size_t)gr * KDIM + k0 + sc * 8;
                va = *(const float4*)p;
                vb = *(const float4*)(p + 4);
            }
            uint4 u;
            u.x = (unsigned)f2bf(va.x * ns) | ((unsigned)f2bf(va.y * ns) << 16);
            u.y = (unsigned)f2bf(va.z * ns) | ((unsigned)f2bf(va.w * ns) << 16);
            u.z = (unsigned)f2bf(vb.x * ns) | ((unsigned)f2bf(vb.y * ns) << 16);
            u.w = (unsigned)f2bf(vb.z * ns) | ((unsigned)f2bf(vb.w * ns) << 16);
            *(uint4*)&As[sr * 40 + sc * 8] = u;
        } else {
            const unsigned short* A = (const unsigned short*)Aptr;
            uint4 u = make_uint4(0, 0, 0, 0);
            if (rok) u = *(const uint4*)(A + (size_t)gr * KDIM + k0 + sc * 8);
            *(uint4*)&As[sr * 40 + sc * 8] = u;
        }
        // ---- stage B (256x32 bf16) ----
#pragma unroll
        for (int i = 0; i < 4; i++) {
            int idx = tid + i * 256;
            int n = idx >> 2, ck = idx & 3;
            uint4 w = *(const uint4*)(Wt + (size_t)n * KDIM + k0 + ck * 8);
            *(uint4*)&Bs[n * 40 + ck * 8] = w;
        }
        __syncthreads();
        // ---- fragments & MFMA ----
        const int fr = ln & 15;
        const int kg = (ln >> 4) * 8;
        v8bf af[4], bfr[4];
#pragma unroll
        for (int mr = 0; mr < 4; mr++)
            af[mr] = *(const v8bf*)&As[(mr * 16 + fr) * 40 + kg];
#pragma unroll
        for (int nr = 0; nr < 4; nr++)
            bfr[nr] = *(const v8bf*)&Bs[(wv * 64 + nr * 16 + fr) * 40 + kg];
#pragma unroll
        for (int mr = 0; mr < 4; mr++)
#pragma unroll
            for (int nr = 0; nr < 4; nr++)
                acc[mr][nr] = __builtin_amdgcn_mfma_f32_16x16x32_bf16(
                    bfr[nr], af[mr], acc[mr][nr], 0, 0, 0);
        __syncthreads();
    }
    // ---- epilogue: fp8 pack, 1 dword per (mr,nr) per lane ----
#pragma unroll
    for (int mr = 0; mr < 4; mr++) {
        int grow = m0 + mr * 16 + (ln & 15);
        if (grow < M) {
#pragma unroll
            for (int nr = 0; nr < 4; nr++) {
                unsigned u = fp8_enc(acc[mr][nr][0]) | (fp8_enc(acc[mr][nr][1]) << 8) |
                             (fp8_enc(acc[mr][nr][2]) << 16) | (fp8_enc(acc[mr][nr][3]) << 24);
                *(unsigned*)(Xout + (size_t)grow * 256 + wv * 64 + nr * 16 + (ln >> 4) * 4) = u;
            }
        }
    }
}

// ---------- aggregation: h(bf16) = leaky(segsum(x_fp8[esrc]) * nd + b) [* post_scale] ----------
__global__ __launch_bounds__(256) void agg_fp8_kernel(
    const unsigned char* __restrict__ xb, const int* __restrict__ esrc,
    const int* __restrict__ row_start, const int* __restrict__ degI,
    const float* __restrict__ norm_dst, const float* __restrict__ post_scale,
    const float* __restrict__ bias, unsigned short* __restrict__ hout, int n) {
    int wave = threadIdx.x >> 6;
    int lane = threadIdx.x & 63;
    int node = blockIdx.x * 4 + wave;
    if (node >= n) return;
    int start = row_start[node];
    int cnt = degI[node];

    float a0 = 0.f, a1 = 0.f, a2 = 0.f, a3 = 0.f;
    int j = 0;
    for (; j + 4 <= cnt; j += 4) {
        int s0 = esrc[start + j + 0];
        int s1 = esrc[start + j + 1];
        int s2 = esrc[start + j + 2];
        int s3 = esrc[start + j + 3];
        unsigned v0 = *(const unsigned*)(xb + (size_t)s0 * 256 + lane * 4);
        unsigned v1 = *(const unsigned*)(xb + (size_t)s1 * 256 + lane * 4);
        unsigned v2 = *(const unsigned*)(xb + (size_t)s2 * 256 + lane * 4);
        unsigned v3 = *(const unsigned*)(xb + (size_t)s3 * 256 + lane * 4);
        a0 += fp8_dec(v0 & 255u) + fp8_dec(v1 & 255u) + fp8_dec(v2 & 255u) + fp8_dec(v3 & 255u);
        a1 += fp8_dec((v0 >> 8) & 255u) + fp8_dec((v1 >> 8) & 255u) + fp8_dec((v2 >> 8) & 255u) + fp8_dec((v3 >> 8) & 255u);
        a2 += fp8_dec((v0 >> 16) & 255u) + fp8_dec((v1 >> 16) & 255u) + fp8_dec((v2 >> 16) & 255u) + fp8_dec((v3 >> 16) & 255u);
        a3 += fp8_dec(v0 >> 24) + fp8_dec(v1 >> 24) + fp8_dec(v2 >> 24) + fp8_dec(v3 >> 24);
    }
    for (; j < cnt; j++) {
        int s = esrc[start + j];
        unsigned v = *(const unsigned*)(xb + (size_t)s * 256 + lane * 4);
        a0 += fp8_dec(v & 255u);
        a1 += fp8_dec((v >> 8) & 255u);
        a2 += fp8_dec((v >> 16) & 255u);
        a3 += fp8_dec(v >> 24);
    }
    float nd = norm_dst[node];
    float ps = post_scale ? post_scale[node] : 1.0f;
    float4 bv = *(const float4*)(bias + lane * 4);
    float r0 = a0 * nd + bv.x;
    float r1 = a1 * nd + bv.y;
    float r2 = a2 * nd + bv.z;
    float r3 = a3 * nd + bv.w;
    r0 = ((r0 >= 0.f) ? r0 : 0.01f * r0) * ps;
    r1 = ((r1 >= 0.f) ? r1 : 0.01f * r1) * ps;
    r2 = ((r2 >= 0.f) ? r2 : 0.01f * r2) * ps;
    r3 = ((r3 >= 0.f) ? r3 : 0.01f * r3) * ps;
    ushort4 o;
    o.x = f2bf(r0); o.y = f2bf(r1); o.z = f2bf(r2); o.w = f2bf(r3);
    *(ushort4*)(hout + (size_t)node * 256 + lane * 4) = o;
}

// ---------- pooling (bf16 h) ----------
__global__ void pool_partial_kernel(const unsigned short* __restrict__ h, int n,
                                    float* psum, float* pmax) {
    int b = blockIdx.x, t = threadIdx.x;
    int r0 = b * 128;
    int r1 = min(r0 + 128, n);
    float s = 0.0f, m = -INFINITY;
    for (int r = r0; r < r1; r++) {
        float v = bf2f(h[(size_t)r * 256 + t]);
        s += v;
        m = fmaxf(m, v);
    }
    psum[(size_t)b * 256 + t] = s;
    pmax[(size_t)b * 256 + t] = m;
}

__global__ void pool_final_kernel(const float* __restrict__ psum, const float* __restrict__ pmax,
                                  int nchunks, const unsigned short* __restrict__ h,
                                  const int* __restrict__ node_index, float* pooled) {
    int t = threadIdx.x;  // 256
    float s = 0.0f, m = -INFINITY;
    for (int c = 0; c < nchunks; c++) {
        s += psum[(size_t)c * 256 + t];
        m = fmaxf(m, pmax[(size_t)c * 256 + t]);
    }
    pooled[t] = s;
    pooled[256 + t] = m;
    pooled[512 + t] = bf2f(h[(size_t)(*node_index) * 256 + t]);
}

// ---------- head GEMM: fd = pooled @ Wg (768 x 1024) ----------
__global__ void head_gemm_kernel(const float* __restrict__ pooled,
                                 const float* __restrict__ Wg, float* fd) {
    __shared__ float p[768];
    int t = threadIdx.x;  // 128
    for (int i = t; i < 768; i += 128) p[i] = pooled[i];
    __syncthreads();
    int j = blockIdx.x * 128 + t;
    float s = 0.0f;
#pragma unroll 8
    for (int i = 0; i < 768; i++) s += p[i] * Wg[(size_t)i * 1024 + j];
    fd[j] = s;
}

// ---------- final epilogue ----------
__global__ void head_final_kernel(const float* __restrict__ fd, const float* __restrict__ bg,
                                  const float* __restrict__ eps, float* __restrict__ out) {
    __shared__ float red[512];
    int t = threadIdx.x;  // 512
    float mu = fd[t] + bg[t];
    float sg = fabsf(fd[512 + t] + bg[512 + t]);
    float fn = mu + sg * eps[t];
    out[t] = fn;
    out[512 + t] = mu;
    out[1024 + t] = sg;
    float z = (fn - mu) / sg;
    const float LOG2PI = 1.8378770664093453f;
    float lp = -0.5f * z * z - logf(sg) - 0.5f * LOG2PI;
    red[t] = lp;
    __syncthreads();
    for (int off = 256; off > 0; off >>= 1) {
        if (t < off) red[t] += red[t + off];
        __syncthreads();
    }
    if (t == 0) out[1536] = red[0] / 512.0f;
}

// ---------- launch ----------
extern "C" void kernel_launch(void* const* d_in, const int* in_sizes, int n_in,
                              void* d_out, int out_size, void* d_ws, size_t ws_size,
                              hipStream_t stream) {
    const float* feat = (const float*)d_in[0];
    const int* src    = (const int*)d_in[1];
    const int* dst    = (const int*)d_in[2];
    const int* nodeix = (const int*)d_in[3];
    const float* W1   = (const float*)d_in[4];
    const float* b1   = (const float*)d_in[5];
    const float* W2   = (const float*)d_in[6];
    const float* b2   = (const float*)d_in[7];
    const float* Wg   = (const float*)d_in[8];
    const float* bg   = (const float*)d_in[9];
    const float* eps  = (const float*)d_in[10];
    float* out = (float*)d_out;

    const int N = in_sizes[0] / F_DIM;
    const int E = in_sizes[1];

    char* ws = (char*)d_ws;
    size_t off = 0;
    auto alloc = [&](size_t bytes) -> char* {
        char* p = ws + off;
        off += (bytes + 511) & ~(size_t)511;
        return p;
    };
    int* degO      = (int*)alloc((size_t)N * 4);
    int* degI      = (int*)alloc((size_t)N * 4);
    float* nsrc    = (float*)alloc((size_t)N * 4);
    float* ndst    = (float*)alloc((size_t)N * 4);
    int* row_start = (int*)alloc((size_t)N * 4);
    int* cursor    = (int*)alloc((size_t)N * 4);
    int* blocksums = (int*)alloc(1024);
    int* blockoffs = (int*)alloc(1024);
    int* esrc      = (int*)alloc((size_t)E * 4);
    unsigned short* Wt1 = (unsigned short*)alloc((size_t)256 * F_DIM * 2);
    unsigned short* Wt2 = (unsigned short*)alloc((size_t)256 * H_DIM * 2);
    unsigned char* xbuf = (unsigned char*)alloc((size_t)N * H_DIM);       // fp8
    unsigned short* hs  = (unsigned short*)alloc((size_t)N * H_DIM * 2);  // bf16
    int nchunks = (N + 127) / 128;
    float* psum    = (float*)alloc((size_t)nchunks * 256 * 4);
    float* pmax    = (float*)alloc((size_t)nchunks * 256 * 4);
    float* pooled  = (float*)alloc(768 * 4);
    float* fd      = (float*)alloc(1024 * 4);

    hipMemsetAsync(degO, 0, (size_t)N * 4, stream);
    hipMemsetAsync(degI, 0, (size_t)N * 4, stream);
    hipMemsetAsync(cursor, 0, (size_t)N * 4, stream);

    hist_kernel<<<2048, 256, 0, stream>>>(src, dst, E, degO, degI);
    norm_kernel<<<(N + 255) / 256, 256, 0, stream>>>(degO, degI, N, nsrc, ndst);
    int nb = (N + 1023) / 1024;
    scan1_kernel<<<nb, 256, 0, stream>>>(degI, N, blocksums);
    scan2_kernel<<<1, 1, 0, stream>>>(blocksums, nb, blockoffs);
    scan3_kernel<<<nb, 256, 0, stream>>>(degI, N, blockoffs, row_start);
    csr_fill_kernel<<<2048, 256, 0, stream>>>(src, dst, E, row_start, cursor, esrc);

    wt_kernel<<<(256 * F_DIM + 255) / 256, 256, 0, stream>>>(W1, Wt1, F_DIM);
    wt_kernel<<<(256 * H_DIM + 255) / 256, 256, 0, stream>>>(W2, Wt2, H_DIM);

    int mblocks = (N + 63) / 64;
    // layer 1: x1 = (feat*ns)@W1 -> fp8 ; h1s = leaky(agg*nd + b1)*ns -> bf16
    gemm_mfma_kernel<F_DIM, true><<<mblocks, 256, 0, stream>>>(feat, nsrc, Wt1, xbuf, N);
    agg_fp8_kernel<<<(N + 3) / 4, 256, 0, stream>>>(xbuf, esrc, row_start, degI, ndst, nsrc, b1, hs, N);
    // layer 2: x2 = h1s@W2 -> fp8 ; h2 = leaky(agg*nd + b2) -> bf16
    gemm_mfma_kernel<H_DIM, false><<<mblocks, 256, 0, stream>>>(hs, nullptr, Wt2, xbuf, N);
    agg_fp8_kernel<<<(N + 3) / 4, 256, 0, stream>>>(xbuf, esrc, row_start, degI, ndst, nullptr, b2, hs, N);
    // pooling
    pool_partial_kernel<<<nchunks, 256, 0, stream>>>(hs, N, psum, pmax);
    pool_final_kernel<<<1, 256, 0, stream>>>(psum, pmax, nchunks, hs, nodeix, pooled);
    // head
    head_gemm_kernel<<<8, 128, 0, stream>>>(pooled, Wg, fd);
    head_final_kernel<<<1, 512, 0, stream>>>(fd, bg, eps, out);
}

// Round 4
// 924.831 us; speedup vs baseline: 1.2545x; 1.2545x over previous
//
#include <hip/hip_runtime.h>
#include <math.h>

#define F_DIM 512
#define H_DIM 256

using v8bf  = __attribute__((ext_vector_type(8))) __bf16;
using f32x4 = __attribute__((ext_vector_type(4))) float;

// ---------- scalar format helpers (no half/fp8 API dependencies) ----------
__device__ __forceinline__ float bf2f(unsigned short u) {
    return __uint_as_float(((unsigned int)u) << 16);
}
__device__ __forceinline__ unsigned short f2bf(float f) {
    unsigned int x = __float_as_uint(f);
    unsigned int r = x + 0x7FFFu + ((x >> 16) & 1u);  // RNE
    return (unsigned short)(r >> 16);
}
// OCP e4m3: decode byte -> float (exact, incl. subnormals; no NaN in data)
__device__ __forceinline__ float fp8_dec(unsigned b) {
    unsigned em = b & 0x7Fu;
    float v = (em >= 8u) ? __uint_as_float((em + 960u) << 20)   // 2^(e-7)*(1+m/8)
                         : (float)em * 0.001953125f;            // m * 2^-9
    return (b & 0x80u) ? -v : v;
}
// float -> e4m3 with RNE (|f| << 448 so no saturation path needed)
__device__ __forceinline__ unsigned fp8_enc(float f) {
    unsigned bits = __float_as_uint(f);
    unsigned s = (bits >> 31) << 7;
    unsigned r = bits + 0x7FFFFu + ((bits >> 20) & 1u);   // round mantissa 23->3
    int e = (int)((r >> 23) & 0xFF);
    unsigned em;
    if (e >= 121) em = (unsigned)(((e - 120) << 3) | ((r >> 20) & 7u));
    else          em = (unsigned)__float2int_rn(fabsf(f) * 512.0f);  // subnormal
    return s | em;
}

// ---------- degree histogram ----------
__global__ void hist_kernel(const int* __restrict__ src, const int* __restrict__ dst,
                            int E, int* degO, int* degI) {
    int stride = gridDim.x * blockDim.x;
    for (int e = blockIdx.x * blockDim.x + threadIdx.x; e < E; e += stride) {
        atomicAdd(&degO[src[e]], 1);
        atomicAdd(&degI[dst[e]], 1);
    }
}

// ---------- norms ----------
__global__ void norm_kernel(const int* __restrict__ degO, const int* __restrict__ degI,
                            int n, float* nsrc, float* ndst) {
    int i = blockIdx.x * blockDim.x + threadIdx.x;
    if (i < n) {
        nsrc[i] = rsqrtf(fmaxf((float)degO[i], 1.0f));
        ndst[i] = rsqrtf(fmaxf((float)degI[i], 1.0f));
    }
}

// ---------- exclusive scan of in-degree (3-kernel) ----------
__global__ void scan1_kernel(const int* __restrict__ deg, int n, int* blocksums) {
    __shared__ int sm[256];
    int b = blockIdx.x, t = threadIdx.x;
    int base = b * 1024 + t * 4;
    int s = 0;
#pragma unroll
    for (int i = 0; i < 4; i++) { int idx = base + i; if (idx < n) s += deg[idx]; }
    sm[t] = s; __syncthreads();
    for (int off = 128; off > 0; off >>= 1) {
        if (t < off) sm[t] += sm[t + off];
        __syncthreads();
    }
    if (t == 0) blocksums[b] = sm[0];
}

__global__ void scan2_kernel(const int* __restrict__ blocksums, int nb, int* blockoffs) {
    if (threadIdx.x == 0 && blockIdx.x == 0) {
        int run = 0;
        for (int i = 0; i < nb; i++) { blockoffs[i] = run; run += blocksums[i]; }
    }
}

__global__ void scan3_kernel(const int* __restrict__ deg, int n,
                             const int* __restrict__ blockoffs, int* row_start) {
    __shared__ int sm[256];
    int b = blockIdx.x, t = threadIdx.x;
    int base = b * 1024 + t * 4;
    int v[4]; int s = 0;
#pragma unroll
    for (int i = 0; i < 4; i++) {
        int idx = base + i;
        v[i] = (idx < n) ? deg[idx] : 0;
        s += v[i];
    }
    sm[t] = s; __syncthreads();
    for (int off = 1; off < 256; off <<= 1) {
        int x = sm[t];
        int y = (t >= off) ? sm[t - off] : 0;
        __syncthreads();
        sm[t] = x + y;
        __syncthreads();
    }
    int run = blockoffs[b] + sm[t] - s;
#pragma unroll
    for (int i = 0; i < 4; i++) {
        int idx = base + i;
        if (idx < n) row_start[idx] = run;
        run += v[i];
    }
}

// ---------- CSR fill ----------
__global__ void csr_fill_kernel(const int* __restrict__ src, const int* __restrict__ dst,
                                int E, const int* __restrict__ row_start,
                                int* cursor, int* esrc) {
    int stride = gridDim.x * blockDim.x;
    for (int e = blockIdx.x * blockDim.x + threadIdx.x; e < E; e += stride) {
        int d = dst[e];
        int pos = atomicAdd(&cursor[d], 1);
        esrc[row_start[d] + pos] = src[e];
    }
}

// ---------- weight transpose+cast: Wt[n][k] = bf16(W[k][n]) ----------
__global__ void wt_kernel(const float* __restrict__ W, unsigned short* __restrict__ Wt, int K) {
    int idx = blockIdx.x * 256 + threadIdx.x;  // over 256*K
    if (idx < 256 * K) {
        int n = idx / K, k = idx - n * K;
        Wt[idx] = f2bf(W[(size_t)k * 256 + n]);
    }
}

// ---------- MFMA GEMM: Xout(fp8) = (A [*scale]) @ Wt^T ; Wt is [256][K] bf16 ----------
template<int KDIM, bool A_FP32>
__global__ __launch_bounds__(256) void gemm_mfma_kernel(
    const void* __restrict__ Aptr, const float* __restrict__ scale,
    const unsigned short* __restrict__ Wt, unsigned char* __restrict__ Xout, int M) {
    __shared__ unsigned short As[64 * 40];    // [m][k] pad 8
    __shared__ unsigned short Bs[256 * 40];   // [n][k] pad 8

    const int tid = threadIdx.x;
    const int wv = tid >> 6, ln = tid & 63;
    const int m0 = blockIdx.x * 64;
    const int sr = tid >> 2;        // staging row 0..63
    const int sc = tid & 3;         // staging k-chunk 0..3 (8 elems)

    f32x4 acc[4][4];
#pragma unroll
    for (int i = 0; i < 4; i++)
#pragma unroll
        for (int j = 0; j < 4; j++) acc[i][j] = (f32x4){0.f, 0.f, 0.f, 0.f};

    const int gr = m0 + sr;
    const bool rok = (gr < M);
    float ns = 0.0f;
    if (A_FP32 && rok) ns = scale[gr];

    for (int k0 = 0; k0 < KDIM; k0 += 32) {
        // ---- stage A (64x32 bf16) ----
        if (A_FP32) {
            const float* A = (const float*)Aptr;
            float4 va = make_float4(0, 0, 0, 0), vb = make_float4(0, 0, 0, 0);
            if (rok) {
                const float* p = A + (size_t)gr * KDIM + k0 + sc * 8;
                va = *(const float4*)p;
                vb = *(const float4*)(p + 4);
            }
            uint4 u;
            u.x = (unsigned)f2bf(va.x * ns) | ((unsigned)f2bf(va.y * ns) << 16);
            u.y = (unsigned)f2bf(va.z * ns) | ((unsigned)f2bf(va.w * ns) << 16);
            u.z = (unsigned)f2bf(vb.x * ns) | ((unsigned)f2bf(vb.y * ns) << 16);
            u.w = (unsigned)f2bf(vb.z * ns) | ((unsigned)f2bf(vb.w * ns) << 16);
            *(uint4*)&As[sr * 40 + sc * 8] = u;
        } else {
            const unsigned short* A = (const unsigned short*)Aptr;
            uint4 u = make_uint4(0, 0, 0, 0);
            if (rok) u = *(const uint4*)(A + (size_t)gr * KDIM + k0 + sc * 8);
            *(uint4*)&As[sr * 40 + sc * 8] = u;
        }
        // ---- stage B (256x32 bf16) ----
#pragma unroll
        for (int i = 0; i < 4; i++) {
            int idx = tid + i * 256;
            int n = idx >> 2, ck = idx & 3;
            uint4 w = *(const uint4*)(Wt + (size_t)n * KDIM + k0 + ck * 8);
            *(uint4*)&Bs[n * 40 + ck * 8] = w;
        }
        __syncthreads();
        // ---- fragments & MFMA ----
        const int fr = ln & 15;
        const int kg = (ln >> 4) * 8;
        v8bf af[4], bfr[4];
#pragma unroll
        for (int mr = 0; mr < 4; mr++)
            af[mr] = *(const v8bf*)&As[(mr * 16 + fr) * 40 + kg];
#pragma unroll
        for (int nr = 0; nr < 4; nr++)
            bfr[nr] = *(const v8bf*)&Bs[(wv * 64 + nr * 16 + fr) * 40 + kg];
#pragma unroll
        for (int mr = 0; mr < 4; mr++)
#pragma unroll
            for (int nr = 0; nr < 4; nr++)
                acc[mr][nr] = __builtin_amdgcn_mfma_f32_16x16x32_bf16(
                    bfr[nr], af[mr], acc[mr][nr], 0, 0, 0);
        __syncthreads();
    }
    // ---- epilogue: fp8 pack ----
#pragma unroll
    for (int mr = 0; mr < 4; mr++) {
        int grow = m0 + mr * 16 + (ln & 15);
        if (grow < M) {
#pragma unroll
            for (int nr = 0; nr < 4; nr++) {
                unsigned u = fp8_enc(acc[mr][nr][0]) | (fp8_enc(acc[mr][nr][1]) << 8) |
                             (fp8_enc(acc[mr][nr][2]) << 16) | (fp8_enc(acc[mr][nr][3]) << 24);
                *(unsigned*)(Xout + (size_t)grow * 256 + wv * 64 + nr * 16 + (ln >> 4) * 4) = u;
            }
        }
    }
}

// ---------- aggregation: h(bf16) = leaky(segsum(x_fp8[esrc]) * nd + b) [* post_scale] ----------
__global__ __launch_bounds__(256) void agg_fp8_kernel(
    const unsigned char* __restrict__ xb, const int* __restrict__ esrc,
    const int* __restrict__ row_start, const int* __restrict__ degI,
    const float* __restrict__ norm_dst, const float* __restrict__ post_scale,
    const float* __restrict__ bias, unsigned short* __restrict__ hout, int n) {
    int wave = threadIdx.x >> 6;
    int lane = threadIdx.x & 63;
    int node = blockIdx.x * 4 + wave;
    if (node >= n) return;
    int start = row_start[node];
    int cnt = degI[node];

    float a0 = 0.f, a1 = 0.f, a2 = 0.f, a3 = 0.f;
    int j = 0;
    for (; j + 4 <= cnt; j += 4) {
        int s0 = esrc[start + j + 0];
        int s1 = esrc[start + j + 1];
        int s2 = esrc[start + j + 2];
        int s3 = esrc[start + j + 3];
        unsigned v0 = *(const unsigned*)(xb + (size_t)s0 * 256 + lane * 4);
        unsigned v1 = *(const unsigned*)(xb + (size_t)s1 * 256 + lane * 4);
        unsigned v2 = *(const unsigned*)(xb + (size_t)s2 * 256 + lane * 4);
        unsigned v3 = *(const unsigned*)(xb + (size_t)s3 * 256 + lane * 4);
        a0 += fp8_dec(v0 & 255u) + fp8_dec(v1 & 255u) + fp8_dec(v2 & 255u) + fp8_dec(v3 & 255u);
        a1 += fp8_dec((v0 >> 8) & 255u) + fp8_dec((v1 >> 8) & 255u) + fp8_dec((v2 >> 8) & 255u) + fp8_dec((v3 >> 8) & 255u);
        a2 += fp8_dec((v0 >> 16) & 255u) + fp8_dec((v1 >> 16) & 255u) + fp8_dec((v2 >> 16) & 255u) + fp8_dec((v3 >> 16) & 255u);
        a3 += fp8_dec(v0 >> 24) + fp8_dec(v1 >> 24) + fp8_dec(v2 >> 24) + fp8_dec(v3 >> 24);
    }
    for (; j < cnt; j++) {
        int s = esrc[start + j];
        unsigned v = *(const unsigned*)(xb + (size_t)s * 256 + lane * 4);
        a0 += fp8_dec(v & 255u);
        a1 += fp8_dec((v >> 8) & 255u);
        a2 += fp8_dec((v >> 16) & 255u);
        a3 += fp8_dec(v >> 24);
    }
    float nd = norm_dst[node];
    float ps = post_scale ? post_scale[node] : 1.0f;
    float4 bv = *(const float4*)(bias + lane * 4);
    float r0 = a0 * nd + bv.x;
    float r1 = a1 * nd + bv.y;
    float r2 = a2 * nd + bv.z;
    float r3 = a3 * nd + bv.w;
    r0 = ((r0 >= 0.f) ? r0 : 0.01f * r0) * ps;
    r1 = ((r1 >= 0.f) ? r1 : 0.01f * r1) * ps;
    r2 = ((r2 >= 0.f) ? r2 : 0.01f * r2) * ps;
    r3 = ((r3 >= 0.f) ? r3 : 0.01f * r3) * ps;
    ushort4 o;
    o.x = f2bf(r0); o.y = f2bf(r1); o.z = f2bf(r2); o.w = f2bf(r3);
    *(ushort4*)(hout + (size_t)node * 256 + lane * 4) = o;
}

// ---------- pooling (bf16 h), 3 stages ----------
__global__ void pool_partial_kernel(const unsigned short* __restrict__ h, int n,
                                    float* psum, float* pmax) {
    int b = blockIdx.x, t = threadIdx.x;
    int r0 = b * 128;
    int r1 = min(r0 + 128, n);
    float s = 0.0f, m = -INFINITY;
    for (int r = r0; r < r1; r++) {
        float v = bf2f(h[(size_t)r * 256 + t]);
        s += v;
        m = fmaxf(m, v);
    }
    psum[(size_t)b * 256 + t] = s;
    pmax[(size_t)b * 256 + t] = m;
}

__global__ void pool_mid_kernel(const float* __restrict__ psum, const float* __restrict__ pmax,
                                int nchunks, float* psum2, float* pmax2) {
    int b = blockIdx.x;   // 0..31
    int t = threadIdx.x;  // 256
    float s = 0.0f, m = -INFINITY;
    for (int c = b; c < nchunks; c += 32) {
        s += psum[(size_t)c * 256 + t];
        m = fmaxf(m, pmax[(size_t)c * 256 + t]);
    }
    psum2[(size_t)b * 256 + t] = s;
    pmax2[(size_t)b * 256 + t] = m;
}

__global__ void pool_final_kernel(const float* __restrict__ psum2, const float* __restrict__ pmax2,
                                  const unsigned short* __restrict__ h,
                                  const int* __restrict__ node_index, float* pooled) {
    int t = threadIdx.x;  // 256
    float s = 0.0f, m = -INFINITY;
#pragma unroll
    for (int c = 0; c < 32; c++) {
        s += psum2[(size_t)c * 256 + t];
        m = fmaxf(m, pmax2[(size_t)c * 256 + t]);
    }
    pooled[t] = s;
    pooled[256 + t] = m;
    pooled[512 + t] = bf2f(h[(size_t)(*node_index) * 256 + t]);
}

// ---------- head GEMM (k-split): fdp[kb][j] = sum_{i in kb} pooled[i]*Wg[i][j] ----------
__global__ void head_gemm_kernel(const float* __restrict__ pooled,
                                 const float* __restrict__ Wg, float* fdp) {
    __shared__ float p[96];
    int t = threadIdx.x;  // 128
    int cb = blockIdx.x;  // 0..7 col blocks
    int kb = blockIdx.y;  // 0..7 k blocks (96 each)
    if (t < 96) p[t] = pooled[kb * 96 + t];
    __syncthreads();
    int j = cb * 128 + t;
    float s = 0.0f;
#pragma unroll 8
    for (int i = 0; i < 96; i++) s += p[i] * Wg[(size_t)(kb * 96 + i) * 1024 + j];
    fdp[(size_t)kb * 1024 + j] = s;
}

// ---------- final epilogue (sums the 8 k-partials) ----------
__global__ void head_final_kernel(const float* __restrict__ fdp, const float* __restrict__ bg,
                                  const float* __restrict__ eps, float* __restrict__ out) {
    __shared__ float red[512];
    int t = threadIdx.x;  // 512
    float mu = bg[t];
    float sgr = bg[512 + t];
#pragma unroll
    for (int kb = 0; kb < 8; kb++) {
        mu  += fdp[(size_t)kb * 1024 + t];
        sgr += fdp[(size_t)kb * 1024 + 512 + t];
    }
    float sg = fabsf(sgr);
    float fn = mu + sg * eps[t];
    out[t] = fn;
    out[512 + t] = mu;
    out[1024 + t] = sg;
    float z = (fn - mu) / sg;
    const float LOG2PI = 1.8378770664093453f;
    float lp = -0.5f * z * z - logf(sg) - 0.5f * LOG2PI;
    red[t] = lp;
    __syncthreads();
    for (int off = 256; off > 0; off >>= 1) {
        if (t < off) red[t] += red[t + off];
        __syncthreads();
    }
    if (t == 0) out[1536] = red[0] / 512.0f;
}

// ---------- launch ----------
extern "C" void kernel_launch(void* const* d_in, const int* in_sizes, int n_in,
                              void* d_out, int out_size, void* d_ws, size_t ws_size,
                              hipStream_t stream) {
    const float* feat = (const float*)d_in[0];
    const int* src    = (const int*)d_in[1];
    const int* dst    = (const int*)d_in[2];
    const int* nodeix = (const int*)d_in[3];
    const float* W1   = (const float*)d_in[4];
    const float* b1   = (const float*)d_in[5];
    const float* W2   = (const float*)d_in[6];
    const float* b2   = (const float*)d_in[7];
    const float* Wg   = (const float*)d_in[8];
    const float* bg   = (const float*)d_in[9];
    const float* eps  = (const float*)d_in[10];
    float* out = (float*)d_out;

    const int N = in_sizes[0] / F_DIM;
    const int E = in_sizes[1];

    char* ws = (char*)d_ws;
    size_t off = 0;
    auto alloc = [&](size_t bytes) -> char* {
        char* p = ws + off;
        off += (bytes + 511) & ~(size_t)511;
        return p;
    };
    int* degO      = (int*)alloc((size_t)N * 4);
    int* degI      = (int*)alloc((size_t)N * 4);
    float* nsrc    = (float*)alloc((size_t)N * 4);
    float* ndst    = (float*)alloc((size_t)N * 4);
    int* row_start = (int*)alloc((size_t)N * 4);
    int* cursor    = (int*)alloc((size_t)N * 4);
    int* blocksums = (int*)alloc(1024);
    int* blockoffs = (int*)alloc(1024);
    int* esrc      = (int*)alloc((size_t)E * 4);
    unsigned short* Wt1 = (unsigned short*)alloc((size_t)256 * F_DIM * 2);
    unsigned short* Wt2 = (unsigned short*)alloc((size_t)256 * H_DIM * 2);
    unsigned char* xbuf = (unsigned char*)alloc((size_t)N * H_DIM);       // fp8
    unsigned short* hs  = (unsigned short*)alloc((size_t)N * H_DIM * 2);  // bf16
    int nchunks = (N + 127) / 128;
    float* psum    = (float*)alloc((size_t)nchunks * 256 * 4);
    float* pmax    = (float*)alloc((size_t)nchunks * 256 * 4);
    float* psum2   = (float*)alloc((size_t)32 * 256 * 4);
    float* pmax2   = (float*)alloc((size_t)32 * 256 * 4);
    float* pooled  = (float*)alloc(768 * 4);
    float* fdp     = (float*)alloc((size_t)8 * 1024 * 4);

    hipMemsetAsync(degO, 0, (size_t)N * 4, stream);
    hipMemsetAsync(degI, 0, (size_t)N * 4, stream);
    hipMemsetAsync(cursor, 0, (size_t)N * 4, stream);

    hist_kernel<<<2048, 256, 0, stream>>>(src, dst, E, degO, degI);
    norm_kernel<<<(N + 255) / 256, 256, 0, stream>>>(degO, degI, N, nsrc, ndst);
    int nb = (N + 1023) / 1024;
    scan1_kernel<<<nb, 256, 0, stream>>>(degI, N, blocksums);
    scan2_kernel<<<1, 1, 0, stream>>>(blocksums, nb, blockoffs);
    scan3_kernel<<<nb, 256, 0, stream>>>(degI, N, blockoffs, row_start);
    csr_fill_kernel<<<2048, 256, 0, stream>>>(src, dst, E, row_start, cursor, esrc);

    wt_kernel<<<(256 * F_DIM + 255) / 256, 256, 0, stream>>>(W1, Wt1, F_DIM);
    wt_kernel<<<(256 * H_DIM + 255) / 256, 256, 0, stream>>>(W2, Wt2, H_DIM);

    int mblocks = (N + 63) / 64;
    // layer 1: x1 = (feat*ns)@W1 -> fp8 ; h1s = leaky(agg*nd + b1)*ns -> bf16
    gemm_mfma_kernel<F_DIM, true><<<mblocks, 256, 0, stream>>>(feat, nsrc, Wt1, xbuf, N);
    agg_fp8_kernel<<<(N + 3) / 4, 256, 0, stream>>>(xbuf, esrc, row_start, degI, ndst, nsrc, b1, hs, N);
    // layer 2: x2 = h1s@W2 -> fp8 ; h2 = leaky(agg*nd + b2) -> bf16
    gemm_mfma_kernel<H_DIM, false><<<mblocks, 256, 0, stream>>>(hs, nullptr, Wt2, xbuf, N);
    agg_fp8_kernel<<<(N + 3) / 4, 256, 0, stream>>>(xbuf, esrc, row_start, degI, ndst, nullptr, b2, hs, N);
    // pooling (3-stage)
    pool_partial_kernel<<<nchunks, 256, 0, stream>>>(hs, N, psum, pmax);
    pool_mid_kernel<<<32, 256, 0, stream>>>(psum, pmax, nchunks, psum2, pmax2);
    pool_final_kernel<<<1, 256, 0, stream>>>(psum2, pmax2, hs, nodeix, pooled);
    // head
    head_gemm_kernel<<<dim3(8, 8), 128, 0, stream>>>(pooled, Wg, fdp);
    head_final_kernel<<<1, 512, 0, stream>>>(fdp, bg, eps, out);
}

// Round 5
// 759.408 us; speedup vs baseline: 1.5278x; 1.2178x over previous
//
#include <hip/hip_runtime.h>
#include <math.h>

#define F_DIM 512
#define H_DIM 256
#define NPB 512          // nodes per bucket (power of 2)
#define NBMAX 200        // max buckets (N <= 102400)

using v8bf  = __attribute__((ext_vector_type(8))) __bf16;
using f32x4 = __attribute__((ext_vector_type(4))) float;

// ---------- scalar format helpers ----------
__device__ __forceinline__ float bf2f(unsigned short u) {
    return __uint_as_float(((unsigned int)u) << 16);
}
__device__ __forceinline__ unsigned short f2bf(float f) {
    unsigned int x = __float_as_uint(f);
    unsigned int r = x + 0x7FFFu + ((x >> 16) & 1u);  // RNE
    return (unsigned short)(r >> 16);
}
// OCP e4m3: decode byte -> float (exact, incl. subnormals)
__device__ __forceinline__ float fp8_dec(unsigned b) {
    unsigned em = b & 0x7Fu;
    float v = (em >= 8u) ? __uint_as_float((em + 960u) << 20)
                         : (float)em * 0.001953125f;
    return (b & 0x80u) ? -v : v;
}
// float -> e4m3 with RNE (|f| << 448)
__device__ __forceinline__ unsigned fp8_enc(float f) {
    unsigned bits = __float_as_uint(f);
    unsigned s = (bits >> 31) << 7;
    unsigned r = bits + 0x7FFFFu + ((bits >> 20) & 1u);
    int e = (int)((r >> 23) & 0xFF);
    unsigned em;
    if (e >= 121) em = (unsigned)(((e - 120) << 3) | ((r >> 20) & 7u));
    else          em = (unsigned)__float2int_rn(fabsf(f) * 512.0f);
    return s | em;
}

// ---------- K1: per-bucket edge counts (LDS-private hist) ----------
__global__ __launch_bounds__(256) void bucket_count_kernel(
    const int* __restrict__ src, const int* __restrict__ dst, int E, int nb,
    int* bcntS, int* bcntD) {
    __shared__ int cs[NBMAX], cd[NBMAX];
    for (int i = threadIdx.x; i < nb; i += 256) { cs[i] = 0; cd[i] = 0; }
    __syncthreads();
    int stride = gridDim.x * blockDim.x;
    for (int e = blockIdx.x * blockDim.x + threadIdx.x; e < E; e += stride) {
        atomicAdd(&cs[src[e] >> 9], 1);
        atomicAdd(&cd[dst[e] >> 9], 1);
    }
    __syncthreads();
    for (int i = threadIdx.x; i < nb; i += 256) {
        if (cs[i]) atomicAdd(&bcntS[i], cs[i]);
        if (cd[i]) atomicAdd(&bcntD[i], cd[i]);
    }
}

// ---------- K2: exclusive scan over buckets (1 block) ----------
__global__ void bucket_scan_kernel(const int* __restrict__ bcntS, const int* __restrict__ bcntD,
                                   int nb, int* bbaseS, int* bbaseD, int* bcurS, int* bcurD) {
    __shared__ int s1[256], s2[256];
    int t = threadIdx.x;
    int v1 = (t < nb) ? bcntS[t] : 0;
    int v2 = (t < nb) ? bcntD[t] : 0;
    s1[t] = v1; s2[t] = v2;
    __syncthreads();
    for (int off = 1; off < 256; off <<= 1) {
        int a = s1[t], b = s2[t];
        int a2 = (t >= off) ? s1[t - off] : 0;
        int b2 = (t >= off) ? s2[t - off] : 0;
        __syncthreads();
        s1[t] = a + a2; s2[t] = b + b2;
        __syncthreads();
    }
    if (t < nb) {
        int eS = s1[t] - v1;
        int eD = s2[t] - v2;
        bbaseS[t] = eS; bbaseD[t] = eD;
        bcurS[t] = eS;  bcurD[t] = eD;
    }
}

// ---------- K3: partition edges into bucket-contiguous runs ----------
// psrc[i] = src (for degO);  pdst[i] = src | (dst&511)<<17  (src < 2^17)
__global__ __launch_bounds__(256) void partition_kernel(
    const int* __restrict__ src, const int* __restrict__ dst, int E, int chunk, int nb,
    int* bcurS, int* bcurD, int* __restrict__ psrc, unsigned* __restrict__ pdst) {
    __shared__ int cs[NBMAX], cd[NBMAX], ws[NBMAX], wd[NBMAX];
    int t = threadIdx.x;
    for (int i = t; i < nb; i += 256) { cs[i] = 0; cd[i] = 0; }
    __syncthreads();
    int e0 = blockIdx.x * chunk, e1 = min(e0 + chunk, E);
    for (int e = e0 + t; e < e1; e += 256) {
        atomicAdd(&cs[src[e] >> 9], 1);
        atomicAdd(&cd[dst[e] >> 9], 1);
    }
    __syncthreads();
    for (int i = t; i < nb; i += 256) {
        ws[i] = cs[i] ? atomicAdd(&bcurS[i], cs[i]) : 0;
        wd[i] = cd[i] ? atomicAdd(&bcurD[i], cd[i]) : 0;
    }
    __syncthreads();
    for (int e = e0 + t; e < e1; e += 256) {
        int s = src[e], d = dst[e];
        int pS = atomicAdd(&ws[s >> 9], 1);
        psrc[pS] = s;
        int pD = atomicAdd(&wd[d >> 9], 1);
        pdst[pD] = (unsigned)s | ((unsigned)(d & (NPB - 1)) << 17);
    }
}

// ---------- K4: per-bucket CSR build + degrees ----------
__global__ __launch_bounds__(256) void bucket_csr_kernel(
    const unsigned* __restrict__ pdst, const int* __restrict__ psrc,
    const int* __restrict__ bbaseS, const int* __restrict__ bcntS,
    const int* __restrict__ bbaseD, const int* __restrict__ bcntD,
    int* __restrict__ degO, int* __restrict__ degI,
    int* __restrict__ row_start, int* __restrict__ esrc, int n) {
    __shared__ int deg[NPB];
    __shared__ int cur[NPB];
    __shared__ int ps[256];
    int b = blockIdx.x, t = threadIdx.x;
    int nbase = b << 9;
    // ---- dst side: local degree hist ----
    for (int i = t; i < NPB; i += 256) deg[i] = 0;
    __syncthreads();
    int eb = bbaseD[b], ec = bcntD[b];
    for (int i = t; i < ec; i += 256) atomicAdd(&deg[pdst[eb + i] >> 17], 1);
    __syncthreads();
    // ---- scan 512 bins with 256 threads ----
    int d0 = deg[2 * t], d1 = deg[2 * t + 1];
    ps[t] = d0 + d1;
    __syncthreads();
    for (int off = 1; off < 256; off <<= 1) {
        int v = ps[t];
        int u = (t >= off) ? ps[t - off] : 0;
        __syncthreads();
        ps[t] = v + u;
        __syncthreads();
    }
    int ep = ps[t] - (d0 + d1);   // exclusive prefix of pair
    int n0 = nbase + 2 * t, n1 = nbase + 2 * t + 1;
    if (n0 < n) { degI[n0] = d0; row_start[n0] = eb + ep; }
    if (n1 < n) { degI[n1] = d1; row_start[n1] = eb + ep + d0; }
    cur[2 * t] = ep;
    cur[2 * t + 1] = ep + d0;
    __syncthreads();
    // ---- scatter src into esrc within bucket window ----
    for (int i = t; i < ec; i += 256) {
        unsigned v = pdst[eb + i];
        int l = v >> 17;
        int p = atomicAdd(&cur[l], 1);
        esrc[eb + p] = (int)(v & 0x1FFFFu);
    }
    // ---- src side: degO ----
    __syncthreads();
    for (int i = t; i < NPB; i += 256) deg[i] = 0;
    __syncthreads();
    int sb = bbaseS[b], sc = bcntS[b];
    for (int i = t; i < sc; i += 256) atomicAdd(&deg[psrc[sb + i] & (NPB - 1)], 1);
    __syncthreads();
    for (int i = t; i < NPB; i += 256) {
        int g = nbase + i;
        if (g < n) degO[g] = deg[i];
    }
}

// ---------- norms ----------
__global__ void norm_kernel(const int* __restrict__ degO, const int* __restrict__ degI,
                            int n, float* nsrc, float* ndst) {
    int i = blockIdx.x * blockDim.x + threadIdx.x;
    if (i < n) {
        nsrc[i] = rsqrtf(fmaxf((float)degO[i], 1.0f));
        ndst[i] = rsqrtf(fmaxf((float)degI[i], 1.0f));
    }
}

// ---------- weight transpose+cast: Wt[n][k] = bf16(W[k][n]) ----------
__global__ void wt_kernel(const float* __restrict__ W, unsigned short* __restrict__ Wt, int K) {
    int idx = blockIdx.x * 256 + threadIdx.x;  // over 256*K
    if (idx < 256 * K) {
        int n = idx / K, k = idx - n * K;
        Wt[idx] = f2bf(W[(size_t)k * 256 + n]);
    }
}

// ---------- MFMA GEMM: Xout(fp8) = (A [*scale]) @ Wt^T ; Wt is [256][K] bf16 ----------
template<int KDIM, bool A_FP32>
__global__ __launch_bounds__(256) void gemm_mfma_kernel(
    const void* __restrict__ Aptr, const float* __restrict__ scale,
    const unsigned short* __restrict__ Wt, unsigned char* __restrict__ Xout, int M) {
    __shared__ unsigned short As[64 * 40];    // [m][k] pad 8
    __shared__ unsigned short Bs[256 * 40];   // [n][k] pad 8

    const int tid = threadIdx.x;
    const int wv = tid >> 6, ln = tid & 63;
    const int m0 = blockIdx.x * 64;
    const int sr = tid >> 2;        // staging row 0..63
    const int sc = tid & 3;         // staging k-chunk 0..3 (8 elems)

    f32x4 acc[4][4];
#pragma unroll
    for (int i = 0; i < 4; i++)
#pragma unroll
        for (int j = 0; j < 4; j++) acc[i][j] = (f32x4){0.f, 0.f, 0.f, 0.f};

    const int gr = m0 + sr;
    const bool rok = (gr < M);
    float ns = 0.0f;
    if (A_FP32 && rok) ns = scale[gr];

    for (int k0 = 0; k0 < KDIM; k0 += 32) {
        // ---- stage A (64x32 bf16) ----
        if (A_FP32) {
            const float* A = (const float*)Aptr;
            float4 va = make_float4(0, 0, 0, 0), vb = make_float4(0, 0, 0, 0);
            if (rok) {
                const float* p = A + (size_t)gr * KDIM + k0 + sc * 8;
                va = *(const float4*)p;
                vb = *(const float4*)(p + 4);
            }
            uint4 u;
            u.x = (unsigned)f2bf(va.x * ns) | ((unsigned)f2bf(va.y * ns) << 16);
            u.y = (unsigned)f2bf(va.z * ns) | ((unsigned)f2bf(va.w * ns) << 16);
            u.z = (unsigned)f2bf(vb.x * ns) | ((unsigned)f2bf(vb.y * ns) << 16);
            u.w = (unsigned)f2bf(vb.z * ns) | ((unsigned)f2bf(vb.w * ns) << 16);
            *(uint4*)&As[sr * 40 + sc * 8] = u;
        } else {
            const unsigned short* A = (const unsigned short*)Aptr;
            uint4 u = make_uint4(0, 0, 0, 0);
            if (rok) u = *(const uint4*)(A + (size_t)gr * KDIM + k0 + sc * 8);
            *(uint4*)&As[sr * 40 + sc * 8] = u;
        }
        // ---- stage B (256x32 bf16) ----
#pragma unroll
        for (int i = 0; i < 4; i++) {
            int idx = tid + i * 256;
            int n = idx >> 2, ck = idx & 3;
            uint4 w = *(const uint4*)(Wt + (size_t)n * KDIM + k0 + ck * 8);
            *(uint4*)&Bs[n * 40 + ck * 8] = w;
        }
        __syncthreads();
        // ---- fragments & MFMA ----
        const int fr = ln & 15;
        const int kg = (ln >> 4) * 8;
        v8bf af[4], bfr[4];
#pragma unroll
        for (int mr = 0; mr < 4; mr++)
            af[mr] = *(const v8bf*)&As[(mr * 16 + fr) * 40 + kg];
#pragma unroll
        for (int nr = 0; nr < 4; nr++)
            bfr[nr] = *(const v8bf*)&Bs[(wv * 64 + nr * 16 + fr) * 40 + kg];
#pragma unroll
        for (int mr = 0; mr < 4; mr++)
#pragma unroll
            for (int nr = 0; nr < 4; nr++)
                acc[mr][nr] = __builtin_amdgcn_mfma_f32_16x16x32_bf16(
                    bfr[nr], af[mr], acc[mr][nr], 0, 0, 0);
        __syncthreads();
    }
    // ---- epilogue: fp8 pack ----
#pragma unroll
    for (int mr = 0; mr < 4; mr++) {
        int grow = m0 + mr * 16 + (ln & 15);
        if (grow < M) {
#pragma unroll
            for (int nr = 0; nr < 4; nr++) {
                unsigned u = fp8_enc(acc[mr][nr][0]) | (fp8_enc(acc[mr][nr][1]) << 8) |
                             (fp8_enc(acc[mr][nr][2]) << 16) | (fp8_enc(acc[mr][nr][3]) << 24);
                *(unsigned*)(Xout + (size_t)grow * 256 + wv * 64 + nr * 16 + (ln >> 4) * 4) = u;
            }
        }
    }
}

// ---------- aggregation: h(bf16) = leaky(segsum(x_fp8[esrc]) * nd + b) [* post_scale] ----------
__global__ __launch_bounds__(256) void agg_fp8_kernel(
    const unsigned char* __restrict__ xb, const int* __restrict__ esrc,
    const int* __restrict__ row_start, const int* __restrict__ degI,
    const float* __restrict__ norm_dst, const float* __restrict__ post_scale,
    const float* __restrict__ bias, unsigned short* __restrict__ hout, int n) {
    int wave = threadIdx.x >> 6;
    int lane = threadIdx.x & 63;
    int node = blockIdx.x * 4 + wave;
    if (node >= n) return;
    int start = row_start[node];
    int cnt = degI[node];

    float a0 = 0.f, a1 = 0.f, a2 = 0.f, a3 = 0.f;
    int j = 0;
    for (; j + 4 <= cnt; j += 4) {
        int s0 = esrc[start + j + 0];
        int s1 = esrc[start + j + 1];
        int s2 = esrc[start + j + 2];
        int s3 = esrc[start + j + 3];
        unsigned v0 = *(const unsigned*)(xb + (size_t)s0 * 256 + lane * 4);
        unsigned v1 = *(const unsigned*)(xb + (size_t)s1 * 256 + lane * 4);
        unsigned v2 = *(const unsigned*)(xb + (size_t)s2 * 256 + lane * 4);
        unsigned v3 = *(const unsigned*)(xb + (size_t)s3 * 256 + lane * 4);
        a0 += fp8_dec(v0 & 255u) + fp8_dec(v1 & 255u) + fp8_dec(v2 & 255u) + fp8_dec(v3 & 255u);
        a1 += fp8_dec((v0 >> 8) & 255u) + fp8_dec((v1 >> 8) & 255u) + fp8_dec((v2 >> 8) & 255u) + fp8_dec((v3 >> 8) & 255u);
        a2 += fp8_dec((v0 >> 16) & 255u) + fp8_dec((v1 >> 16) & 255u) + fp8_dec((v2 >> 16) & 255u) + fp8_dec((v3 >> 16) & 255u);
        a3 += fp8_dec(v0 >> 24) + fp8_dec(v1 >> 24) + fp8_dec(v2 >> 24) + fp8_dec(v3 >> 24);
    }
    for (; j < cnt; j++) {
        int s = esrc[start + j];
        unsigned v = *(const unsigned*)(xb + (size_t)s * 256 + lane * 4);
        a0 += fp8_dec(v & 255u);
        a1 += fp8_dec((v >> 8) & 255u);
        a2 += fp8_dec((v >> 16) & 255u);
        a3 += fp8_dec(v >> 24);
    }
    float nd = norm_dst[node];
    float ps = post_scale ? post_scale[node] : 1.0f;
    float4 bv = *(const float4*)(bias + lane * 4);
    float r0 = a0 * nd + bv.x;
    float r1 = a1 * nd + bv.y;
    float r2 = a2 * nd + bv.z;
    float r3 = a3 * nd + bv.w;
    r0 = ((r0 >= 0.f) ? r0 : 0.01f * r0) * ps;
    r1 = ((r1 >= 0.f) ? r1 : 0.01f * r1) * ps;
    r2 = ((r2 >= 0.f) ? r2 : 0.01f * r2) * ps;
    r3 = ((r3 >= 0.f) ? r3 : 0.01f * r3) * ps;
    ushort4 o;
    o.x = f2bf(r0); o.y = f2bf(r1); o.z = f2bf(r2); o.w = f2bf(r3);
    *(ushort4*)(hout + (size_t)node * 256 + lane * 4) = o;
}

// ---------- pooling (bf16 h), 3 stages ----------
__global__ void pool_partial_kernel(const unsigned short* __restrict__ h, int n,
                                    float* psum, float* pmax) {
    int b = blockIdx.x, t = threadIdx.x;
    int r0 = b * 128;
    int r1 = min(r0 + 128, n);
    float s = 0.0f, m = -INFINITY;
    for (int r = r0; r < r1; r++) {
        float v = bf2f(h[(size_t)r * 256 + t]);
        s += v;
        m = fmaxf(m, v);
    }
    psum[(size_t)b * 256 + t] = s;
    pmax[(size_t)b * 256 + t] = m;
}

__global__ void pool_mid_kernel(const float* __restrict__ psum, const float* __restrict__ pmax,
                                int nchunks, float* psum2, float* pmax2) {
    int b = blockIdx.x;   // 0..31
    int t = threadIdx.x;  // 256
    float s = 0.0f, m = -INFINITY;
    for (int c = b; c < nchunks; c += 32) {
        s += psum[(size_t)c * 256 + t];
        m = fmaxf(m, pmax[(size_t)c * 256 + t]);
    }
    psum2[(size_t)b * 256 + t] = s;
    pmax2[(size_t)b * 256 + t] = m;
}

__global__ void pool_final_kernel(const float* __restrict__ psum2, const float* __restrict__ pmax2,
                                  const unsigned short* __restrict__ h,
                                  const int* __restrict__ node_index, float* pooled) {
    int t = threadIdx.x;  // 256
    float s = 0.0f, m = -INFINITY;
#pragma unroll
    for (int c = 0; c < 32; c++) {
        s += psum2[(size_t)c * 256 + t];
        m = fmaxf(m, pmax2[(size_t)c * 256 + t]);
    }
    pooled[t] = s;
    pooled[256 + t] = m;
    pooled[512 + t] = bf2f(h[(size_t)(*node_index) * 256 + t]);
}

// ---------- head GEMM (k-split): fdp[kb][j] = sum_{i in kb} pooled[i]*Wg[i][j] ----------
__global__ void head_gemm_kernel(const float* __restrict__ pooled,
                                 const float* __restrict__ Wg, float* fdp) {
    __shared__ float p[96];
    int t = threadIdx.x;  // 128
    int cb = blockIdx.x;  // 0..7 col blocks
    int kb = blockIdx.y;  // 0..7 k blocks (96 each)
    if (t < 96) p[t] = pooled[kb * 96 + t];
    __syncthreads();
    int j = cb * 128 + t;
    float s = 0.0f;
#pragma unroll 8
    for (int i = 0; i < 96; i++) s += p[i] * Wg[(size_t)(kb * 96 + i) * 1024 + j];
    fdp[(size_t)kb * 1024 + j] = s;
}

// ---------- final epilogue (sums the 8 k-partials) ----------
__global__ void head_final_kernel(const float* __restrict__ fdp, const float* __restrict__ bg,
                                  const float* __restrict__ eps, float* __restrict__ out) {
    __shared__ float red[512];
    int t = threadIdx.x;  // 512
    float mu = bg[t];
    float sgr = bg[512 + t];
#pragma unroll
    for (int kb = 0; kb < 8; kb++) {
        mu  += fdp[(size_t)kb * 1024 + t];
        sgr += fdp[(size_t)kb * 1024 + 512 + t];
    }
    float sg = fabsf(sgr);
    float fn = mu + sg * eps[t];
    out[t] = fn;
    out[512 + t] = mu;
    out[1024 + t] = sg;
    float z = (fn - mu) / sg;
    const float LOG2PI = 1.8378770664093453f;
    float lp = -0.5f * z * z - logf(sg) - 0.5f * LOG2PI;
    red[t] = lp;
    __syncthreads();
    for (int off = 256; off > 0; off >>= 1) {
        if (t < off) red[t] += red[t + off];
        __syncthreads();
    }
    if (t == 0) out[1536] = red[0] / 512.0f;
}

// ---------- launch ----------
extern "C" void kernel_launch(void* const* d_in, const int* in_sizes, int n_in,
                              void* d_out, int out_size, void* d_ws, size_t ws_size,
                              hipStream_t stream) {
    const float* feat = (const float*)d_in[0];
    const int* src    = (const int*)d_in[1];
    const int* dst    = (const int*)d_in[2];
    const int* nodeix = (const int*)d_in[3];
    const float* W1   = (const float*)d_in[4];
    const float* b1   = (const float*)d_in[5];
    const float* W2   = (const float*)d_in[6];
    const float* b2   = (const float*)d_in[7];
    const float* Wg   = (const float*)d_in[8];
    const float* bg   = (const float*)d_in[9];
    const float* eps  = (const float*)d_in[10];
    float* out = (float*)d_out;

    const int N = in_sizes[0] / F_DIM;
    const int E = in_sizes[1];
    const int nb = (N + NPB - 1) / NPB;   // 196 buckets

    char* ws = (char*)d_ws;
    size_t off = 0;
    auto alloc = [&](size_t bytes) -> char* {
        char* p = ws + off;
        off += (bytes + 511) & ~(size_t)511;
        return p;
    };
    int* degO      = (int*)alloc((size_t)N * 4);
    int* degI      = (int*)alloc((size_t)N * 4);
    float* nsrc    = (float*)alloc((size_t)N * 4);
    float* ndst    = (float*)alloc((size_t)N * 4);
    int* row_start = (int*)alloc((size_t)N * 4);
    int* bcntS     = (int*)alloc(NBMAX * 4);
    int* bcntD     = (int*)alloc(NBMAX * 4);
    int* bbaseS    = (int*)alloc(NBMAX * 4);
    int* bbaseD    = (int*)alloc(NBMAX * 4);
    int* bcurS     = (int*)alloc(NBMAX * 4);
    int* bcurD     = (int*)alloc(NBMAX * 4);
    int* psrc      = (int*)alloc((size_t)E * 4);
    unsigned* pdst = (unsigned*)alloc((size_t)E * 4);
    int* esrc      = (int*)alloc((size_t)E * 4);
    unsigned short* Wt1 = (unsigned short*)alloc((size_t)256 * F_DIM * 2);
    unsigned short* Wt2 = (unsigned short*)alloc((size_t)256 * H_DIM * 2);
    unsigned char* xbuf = (unsigned char*)alloc((size_t)N * H_DIM);       // fp8
    unsigned short* hs  = (unsigned short*)alloc((size_t)N * H_DIM * 2);  // bf16
    int nchunks = (N + 127) / 128;
    float* psum    = (float*)alloc((size_t)nchunks * 256 * 4);
    float* pmax    = (float*)alloc((size_t)nchunks * 256 * 4);
    float* psum2   = (float*)alloc((size_t)32 * 256 * 4);
    float* pmax2   = (float*)alloc((size_t)32 * 256 * 4);
    float* pooled  = (float*)alloc(768 * 4);
    float* fdp     = (float*)alloc((size_t)8 * 1024 * 4);

    hipMemsetAsync(bcntS, 0, NBMAX * 4, stream);
    hipMemsetAsync(bcntD, 0, NBMAX * 4, stream);

    // ---- graph build (bucketed, LDS-atomic) ----
    bucket_count_kernel<<<1024, 256, 0, stream>>>(src, dst, E, nb, bcntS, bcntD);
    bucket_scan_kernel<<<1, 256, 0, stream>>>(bcntS, bcntD, nb, bbaseS, bbaseD, bcurS, bcurD);
    int chunk = (E + 255) / 256;
    partition_kernel<<<256, 256, 0, stream>>>(src, dst, E, chunk, nb, bcurS, bcurD, psrc, pdst);
    bucket_csr_kernel<<<nb, 256, 0, stream>>>(pdst, psrc, bbaseS, bcntS, bbaseD, bcntD,
                                              degO, degI, row_start, esrc, N);
    norm_kernel<<<(N + 255) / 256, 256, 0, stream>>>(degO, degI, N, nsrc, ndst);

    wt_kernel<<<(256 * F_DIM + 255) / 256, 256, 0, stream>>>(W1, Wt1, F_DIM);
    wt_kernel<<<(256 * H_DIM + 255) / 256, 256, 0, stream>>>(W2, Wt2, H_DIM);

    int mblocks = (N + 63) / 64;
    // layer 1: x1 = (feat*ns)@W1 -> fp8 ; h1s = leaky(agg*nd + b1)*ns -> bf16
    gemm_mfma_kernel<F_DIM, true><<<mblocks, 256, 0, stream>>>(feat, nsrc, Wt1, xbuf, N);
    agg_fp8_kernel<<<(N + 3) / 4, 256, 0, stream>>>(xbuf, esrc, row_start, degI, ndst, nsrc, b1, hs, N);
    // layer 2: x2 = h1s@W2 -> fp8 ; h2 = leaky(agg*nd + b2) -> bf16
    gemm_mfma_kernel<H_DIM, false><<<mblocks, 256, 0, stream>>>(hs, nullptr, Wt2, xbuf, N);
    agg_fp8_kernel<<<(N + 3) / 4, 256, 0, stream>>>(xbuf, esrc, row_start, degI, ndst, nullptr, b2, hs, N);
    // pooling (3-stage)
    pool_partial_kernel<<<nchunks, 256, 0, stream>>>(hs, N, psum, pmax);
    pool_mid_kernel<<<32, 256, 0, stream>>>(psum, pmax, nchunks, psum2, pmax2);
    pool_final_kernel<<<1, 256, 0, stream>>>(psum2, pmax2, hs, nodeix, pooled);
    // head
    head_gemm_kernel<<<dim3(8, 8), 128, 0, stream>>>(pooled, Wg, fdp);
    head_final_kernel<<<1, 512, 0, stream>>>(fdp, bg, eps, out);
}